// Round 1
// baseline (230.273 us; speedup 1.0000x reference)
//
#include <hip/hip_runtime.h>

// DCNv4 on gfx950 — bf16 MFMA pipeline, fragment-swizzled operands.
// R8: split om_sample into (K3a) dense M=64 om GEMM -> omP planes and
// (K3b) sampler with zero-padded 66x66 value plane in LDS (gathers become
// near-linear ds_read_b128; border zeros replace validity flags).
// KW: weights -> bf16 fragment-swizzled
// KF: dwconv3x3 + value GEMM (block = image row) -> xdwF, value_g
// K3a: om = xdw @ om_w + b  (M=64, A in LDS, B read once/block) -> omP
// K3b: bilinear sampling from LDS plane -> sampledF (frag layout)
// K4: out = sampledF @ op_wF (M=64, fp32 NHWC out)

typedef __bf16 bf16_t;
typedef bf16_t bf16x8 __attribute__((ext_vector_type(8)));
typedef bf16_t bf16x4 __attribute__((ext_vector_type(4)));
typedef float f32x4 __attribute__((ext_vector_type(4)));

namespace {
constexpr int NN = 8, HH = 64, WW = 64, CC = 256;
constexpr int G = 32, GC = 8, OMD = 864;      // G*9*3
constexpr int NPIX = NN * HH * WW;            // 32768
}

// fragment-swizzled flat index for a [rows][256] bf16 matrix
__device__ __forceinline__ size_t fragIdx(int row, int c) {
  return ((size_t)(row >> 4) * 4096) + ((c >> 5) * 512) + (((c >> 3) & 3) * 128) +
         ((row & 15) * 8) + (c & 7);
}

// ---------------- KW: weights -> bf16 fragment-swizzled, via LDS transpose ----
__global__ __launch_bounds__(256) void convert_weights_kernel(
    const float* __restrict__ om_w, const float* __restrict__ vp_w,
    const float* __restrict__ op_w, bf16_t* __restrict__ om_wF,
    bf16_t* __restrict__ vp_wF, bf16_t* __restrict__ op_wF) {
  __shared__ float s_t[64][65];
  const int b = blockIdx.x, t = threadIdx.x;
  const float* src;
  bf16_t* dst;
  int ld, ncols, nt, kt;
  if (b < 56) {
    src = om_w; dst = om_wF; ld = OMD; ncols = OMD; kt = b / 14; nt = b % 14;
  } else if (b < 72) {
    const int i = b - 56;
    src = vp_w; dst = vp_wF; ld = CC; ncols = CC; kt = i >> 2; nt = i & 3;
  } else {
    const int i = b - 72;
    src = op_w; dst = op_wF; ld = CC; ncols = CC; kt = i >> 2; nt = i & 3;
  }
  const int nl = t & 63, kh = t >> 6;
  const int n = nt * 64 + nl;
#pragma unroll
  for (int i = 0; i < 16; ++i) {
    const int kl = kh * 16 + i;
    s_t[kl][nl] = (n < ncols) ? src[(size_t)(kt * 64 + kl) * ld + n] : 0.0f;
  }
  __syncthreads();
  const int lane = t & 63, kq = lane >> 4, n15 = lane & 15, n16 = t >> 6;
#pragma unroll
  for (int it = 0; it < 2; ++it) {
    bf16x8 v;
#pragma unroll
    for (int j = 0; j < 8; ++j) v[j] = (bf16_t)s_t[it * 32 + kq * 8 + j][n16 * 16 + n15];
    const size_t off = (size_t)(nt * 4 + n16) * 4096 + (size_t)(kt * 2 + it) * 512 +
                       kq * 128 + n15 * 8;
    *(bf16x8*)(dst + off) = v;
  }
}

// ---------------- KF: fused dwconv3x3 + value GEMM; block = one image row ----
__global__ __launch_bounds__(512, 4) void dwconv_value_kernel(
    const float* __restrict__ x, const float* __restrict__ dw_w,
    const float* __restrict__ dw_b, const bf16_t* __restrict__ vp_wF,
    const float* __restrict__ vp_b, bf16_t* __restrict__ xdwF,
    bf16_t* __restrict__ value_g) {
  __shared__ bf16_t s_xf[64 * 256];  // x bf16 fragments for this row's 4 m-tiles

  const int t = threadIdx.x;
  const int row = blockIdx.x;        // img*64 + y
  const int y = row & 63;
  const int img = row >> 6;

  // ---- Phase A: dwconv
  {
    const int cq = (t & 63) * 4;   // channel base
    const int seg = t >> 6;        // 8-px segment
    const bool up = (y > 0), dn = (y < HH - 1);
    const float* xrow = x + (size_t)row * WW * CC + cq;

    const float4 bias = *(const float4*)&dw_b[cq];
    float4 dw[9];
#pragma unroll
    for (int i = 0; i < 9; ++i) dw[i] = *(const float4*)&dw_w[(size_t)i * CC + cq];

    const float4 zero = make_float4(0.f, 0.f, 0.f, 0.f);
    auto loadcol = [&](int xx, float4 c[3]) {
      if (xx < 0 || xx >= WW) { c[0] = c[1] = c[2] = zero; return; }
      c[0] = up ? *(const float4*)(xrow + ((size_t)xx - WW) * CC) : zero;
      c[1] = *(const float4*)(xrow + (size_t)xx * CC);
      c[2] = dn ? *(const float4*)(xrow + ((size_t)xx + WW) * CC) : zero;
    };

    const int x0 = seg * 8;
    float4 cm[3], cc[3], cp[3];
    loadcol(x0 - 1, cm);
    loadcol(x0, cc);

    for (int xx = x0; xx < x0 + 8; ++xx) {
      loadcol(xx + 1, cp);
      float4 a = bias;
#pragma unroll
      for (int r = 0; r < 3; ++r) {
        const float4 w0 = dw[r * 3 + 0], w1 = dw[r * 3 + 1], w2 = dw[r * 3 + 2];
        a.x = fmaf(cm[r].x, w0.x, fmaf(cc[r].x, w1.x, fmaf(cp[r].x, w2.x, a.x)));
        a.y = fmaf(cm[r].y, w0.y, fmaf(cc[r].y, w1.y, fmaf(cp[r].y, w2.y, a.y)));
        a.z = fmaf(cm[r].z, w0.z, fmaf(cc[r].z, w1.z, fmaf(cp[r].z, w2.z, a.z)));
        a.w = fmaf(cm[r].w, w0.w, fmaf(cc[r].w, w1.w, fmaf(cp[r].w, w2.w, a.w)));
      }
      const int pix = row * WW + xx;
      bf16x4 av, cv;
      av[0] = (bf16_t)a.x; av[1] = (bf16_t)a.y; av[2] = (bf16_t)a.z; av[3] = (bf16_t)a.w;
      cv[0] = (bf16_t)cc[1].x; cv[1] = (bf16_t)cc[1].y;
      cv[2] = (bf16_t)cc[1].z; cv[3] = (bf16_t)cc[1].w;
      *(bf16x4*)&xdwF[fragIdx(pix, cq)] = av;
      const int lf = (xx >> 4) * 4096 + ((cq >> 5) * 512) + (((cq >> 3) & 3) * 128) +
                     ((xx & 15) * 8) + (cq & 7);
      *(bf16x4*)&s_xf[lf] = cv;
#pragma unroll
      for (int r = 0; r < 3; ++r) { cm[r] = cc[r]; cc[r] = cp[r]; }
    }
  }
  __syncthreads();

  // ---- Phase B: value GEMM (M=64 from LDS, N=256)
  {
    const int lane = t & 63;
    const int wave = t >> 6;
    const int mq = wave >> 1;      // m-tile 0..3
    const int nh = wave & 1;       // n-half
    const int m = lane & 15;
    const int kq = lane >> 4;

    const bf16_t* Ap = s_xf + mq * 4096 + lane * 8;
    const bf16_t* Bp = vp_wF + (size_t)(nh * 8) * 4096 + lane * 8;

    f32x4 acc[8] = {};
#pragma unroll
    for (int ks = 0; ks < 8; ++ks) {
      const bf16x8 a = *(const bf16x8*)(Ap + ks * 512);
#pragma unroll
      for (int i = 0; i < 8; ++i) {
        const bf16x8 b = *(const bf16x8*)(Bp + (size_t)i * 4096 + ks * 512);
        acc[i] = __builtin_amdgcn_mfma_f32_16x16x32_bf16(a, b, acc[i], 0, 0, 0);
      }
    }

#pragma unroll
    for (int i = 0; i < 8; ++i) {
      const int n = (nh * 8 + i) * 16 + m;
      const float bs = vp_b[n];
      const int g = n >> 3, c = n & 7;
      bf16_t* plane = value_g + ((size_t)(img * G + g) << 15) + c;
#pragma unroll
      for (int r = 0; r < 4; ++r) {
        const int pl = mq * 16 + kq * 4 + r;           // pixel local 0..63
        const int pin = y * 64 + pl;                   // pixel within image
        plane[(size_t)pin * GC] = (bf16_t)(acc[i][r] + bs);
      }
    }
  }
}

// ---------------- K3a: om GEMM, M=64/block, B read once per block ----------
// omP layout: [img][g][pixInImg][32] bf16 (27 of 32 used) -> 64B/px coalesced
__global__ __launch_bounds__(512, 2) void om_gemm_kernel(
    const bf16_t* __restrict__ xdwF, const bf16_t* __restrict__ om_wF,
    const float* __restrict__ om_b, bf16_t* __restrict__ omP) {
  __shared__ bf16_t s_a[64 * 256];  // 32 KB, frag layout, 4 m-tiles

  const int t = threadIdx.x;
  const int lane = t & 63;
  const int wave = t >> 6;  // 0..7, each owns 7 n-tiles x 4 m-tiles

  {
    const bf16_t* src = xdwF + (size_t)blockIdx.x * 16384;
#pragma unroll
    for (int i = 0; i < 4; ++i) {
      const int idx = (i * 512 + t) * 8;
      *(bf16x8*)(s_a + idx) = *(const bf16x8*)(src + idx);
    }
  }
  __syncthreads();

  const int m = lane & 15;
  const int kq = lane >> 4;
  const bf16_t* Bp = om_wF + (size_t)(wave * 7) * 4096 + lane * 8;

  f32x4 acc[4][7] = {};
#pragma unroll
  for (int ks = 0; ks < 8; ++ks) {
    bf16x8 a[4];
#pragma unroll
    for (int mt = 0; mt < 4; ++mt)
      a[mt] = *(const bf16x8*)(s_a + mt * 4096 + ks * 512 + lane * 8);
#pragma unroll
    for (int i = 0; i < 7; ++i) {
      const bf16x8 b = *(const bf16x8*)(Bp + (size_t)i * 4096 + ks * 512);
#pragma unroll
      for (int mt = 0; mt < 4; ++mt)
        acc[mt][i] =
            __builtin_amdgcn_mfma_f32_16x16x32_bf16(a[mt], b, acc[mt][i], 0, 0, 0);
    }
  }

  const int pix0 = blockIdx.x * 64;
  const int img = pix0 >> 12;        // 64 | 4096, so img constant per block
  const int pin0 = pix0 & 4095;
#pragma unroll
  for (int i = 0; i < 7; ++i) {
    const int nt = wave * 7 + i;
    if (nt < 54) {
      const int n = nt * 16 + m;
      const float bs = om_b[n];
      const int g = n / 27;
      const int j = n - g * 27;
      bf16_t* dst = omP + ((size_t)(img * G + g) * 4096 + pin0) * 32 + j;
#pragma unroll
      for (int mt = 0; mt < 4; ++mt)
#pragma unroll
        for (int r = 0; r < 4; ++r) {
          const int pl = mt * 16 + kq * 4 + r;
          dst[(size_t)pl * 32] = (bf16_t)(acc[mt][i][r] + bs);
        }
    }
  }
}

// ---------------- K3b: sampling; block = (img, g, half); plane in LDS --------
// 66x66 zero-padded plane: clamp coords to [-1,64] -> border zeros make
// out-of-range corners contribute 0 (no validity flags needed).
__global__ __launch_bounds__(512, 2) void sample_kernel(
    const bf16_t* __restrict__ omP, const bf16_t* __restrict__ value_g,
    bf16_t* __restrict__ sampledF) {
  __shared__ bf16x8 s_v[66 * 66];  // 68 KB

  const int t = threadIdx.x;
  const int b = blockIdx.x;
  const int img = b >> 6;
  const int g = (b >> 1) & 31;
  const int half = b & 1;

  // zero the border (260 chunks), fill interior (4096 chunks) — disjoint
  {
    const bf16x8 zv = {};
    for (int i = t; i < 260; i += 512) {
      int Y, X;
      if (i < 66)       { Y = 0;            X = i; }
      else if (i < 132) { Y = 65;           X = i - 66; }
      else if (i < 196) { Y = i - 132 + 1;  X = 0; }
      else              { Y = i - 196 + 1;  X = 65; }
      s_v[Y * 66 + X] = zv;
    }
    const bf16x8* plane = (const bf16x8*)(value_g + ((size_t)(img * G + g) << 15));
#pragma unroll
    for (int i = 0; i < 8; ++i) {
      const int c = i * 512 + t;   // 0..4095
      const int yy = c >> 6, xx = c & 63;
      s_v[(yy + 1) * 66 + (xx + 1)] = plane[c];
    }
  }
  __syncthreads();

  const bf16_t* omBase =
      omP + ((size_t)(img * G + g) * 4096 + (size_t)half * 2048) * 32;

#pragma unroll
  for (int it = 0; it < 4; ++it) {
    const int pl = it * 512 + t;        // 0..2047
    const int px = half * 2048 + pl;    // pixel within image
    const int xw = px & 63;
    const int y = px >> 6;

    const bf16_t* op = omBase + (size_t)pl * 32;
    const bf16x8 o0 = *(const bf16x8*)(op + 0);
    const bf16x8 o1 = *(const bf16x8*)(op + 8);
    const bf16x8 o2 = *(const bf16x8*)(op + 16);
    const bf16x8 o3 = *(const bf16x8*)(op + 24);
    float arr[27];
#pragma unroll
    for (int j = 0; j < 8; ++j) {
      arr[j] = (float)o0[j];
      arr[8 + j] = (float)o1[j];
      arr[16 + j] = (float)o2[j];
    }
#pragma unroll
    for (int j = 0; j < 3; ++j) arr[24 + j] = (float)o3[j];

    float acc[GC];
#pragma unroll
    for (int c = 0; c < GC; ++c) acc[c] = 0.0f;

#pragma unroll
    for (int k = 0; k < 9; ++k) {
      const float pxf = (float)(xw + (k % 3) - 1) + arr[2 * k];
      const float pyf = (float)(y + (k / 3) - 1) + arr[2 * k + 1];
      const float mk = arr[18 + k];
      const float x0f = floorf(pxf), y0f = floorf(pyf);
      const float tx = pxf - x0f, ty = pyf - y0f;
      const int ix = (int)x0f, iy = (int)y0f;

      // clamp to padded range [-1,64]; border zeros kill OOB contributions
      const int iX0 = min(max(ix, -1), 64) + 1;
      const int iX1 = min(max(ix + 1, -1), 64) + 1;
      const int iY0 = min(max(iy, -1), 64) + 1;
      const int iY1 = min(max(iy + 1, -1), 64) + 1;

      const bf16x8 v00 = s_v[iY0 * 66 + iX0];
      const bf16x8 v01 = s_v[iY0 * 66 + iX1];
      const bf16x8 v10 = s_v[iY1 * 66 + iX0];
      const bf16x8 v11 = s_v[iY1 * 66 + iX1];

      const float w00 = mk * (1.0f - ty) * (1.0f - tx);
      const float w01 = mk * (1.0f - ty) * tx;
      const float w10 = mk * ty * (1.0f - tx);
      const float w11 = mk * ty * tx;

#pragma unroll
      for (int c = 0; c < GC; ++c) {
        float s = acc[c];
        s = fmaf(w00, (float)v00[c], s);
        s = fmaf(w01, (float)v01[c], s);
        s = fmaf(w10, (float)v10[c], s);
        s = fmaf(w11, (float)v11[c], s);
        acc[c] = s;
      }
    }

    bf16x8 sv;
#pragma unroll
    for (int c = 0; c < GC; ++c) sv[c] = (bf16_t)acc[c];
    *(bf16x8*)(sampledF + fragIdx(img * 4096 + px, g * 8)) = sv;
  }
}

// ---------------- K4: out = sampledF @ op_wF, M=64/block, fp32 NHWC ----------
__global__ __launch_bounds__(512, 4) void out_gemm_kernel(
    const bf16_t* __restrict__ AF, const bf16_t* __restrict__ BF,
    float* __restrict__ out) {
  const int lane = threadIdx.x & 63;
  const int wave = threadIdx.x >> 6;
  const int mq = wave >> 1;
  const int nh = wave & 1;
  const int mt = blockIdx.x * 4 + mq;
  const int m = lane & 15;
  const int kq = lane >> 4;

  const bf16_t* Ap = AF + (size_t)mt * 4096 + lane * 8;
  const bf16_t* Bp = BF + (size_t)(nh * 8) * 4096 + lane * 8;

  f32x4 acc[8] = {};
#pragma unroll
  for (int ks = 0; ks < 8; ++ks) {
    const bf16x8 a = *(const bf16x8*)(Ap + ks * 512);
#pragma unroll
    for (int i = 0; i < 8; ++i) {
      const bf16x8 b = *(const bf16x8*)(Bp + (size_t)i * 4096 + ks * 512);
      acc[i] = __builtin_amdgcn_mfma_f32_16x16x32_bf16(a, b, acc[i], 0, 0, 0);
    }
  }

#pragma unroll
  for (int i = 0; i < 8; ++i) {
    const int n = (nh * 8 + i) * 16 + m;
#pragma unroll
    for (int r = 0; r < 4; ++r) {
      const int pix = mt * 16 + kq * 4 + r;
      out[(size_t)pix * CC + n] = acc[i][r];
    }
  }
}

extern "C" void kernel_launch(void* const* d_in, const int* in_sizes, int n_in,
                              void* d_out, int out_size, void* d_ws, size_t ws_size,
                              hipStream_t stream) {
  const float* x = (const float*)d_in[0];
  const float* dw_w = (const float*)d_in[1];
  const float* dw_b = (const float*)d_in[2];
  const float* om_w = (const float*)d_in[3];
  const float* om_b = (const float*)d_in[4];
  const float* vp_w = (const float*)d_in[5];
  const float* vp_b = (const float*)d_in[6];
  const float* op_w = (const float*)d_in[7];
  float* out = (float*)d_out;

  // workspace layout (bytes)
  char* ws = (char*)d_ws;
  bf16_t* omP = (bf16_t*)ws;                          // 67,108,864
  bf16_t* value_g = (bf16_t*)(ws + 67108864);         // 16,777,216
  bf16_t* xdwF = (bf16_t*)(ws + 83886080);            // 16,777,216
  bf16_t* sampledF = xdwF;  // alias: xdwF dead after om_gemm (stream-ordered)
  bf16_t* om_wF = (bf16_t*)(ws + 100663296);          // 458,752
  bf16_t* vp_wF = (bf16_t*)(ws + 101122048);          // 131,072
  bf16_t* op_wF = (bf16_t*)(ws + 101253120);          // 131,072

  convert_weights_kernel<<<88, 256, 0, stream>>>(om_w, vp_w, op_w,
                                                 om_wF, vp_wF, op_wF);
  dwconv_value_kernel<<<NN * HH, 512, 0, stream>>>(x, dw_w, dw_b, vp_wF, vp_b,
                                                   xdwF, value_g);
  om_gemm_kernel<<<NPIX / 64, 512, 0, stream>>>(xdwF, om_wF, om_b, omP);
  sample_kernel<<<NPIX / 64, 512, 0, stream>>>(omP, value_g, sampledF);
  out_gemm_kernel<<<NPIX / 64, 512, 0, stream>>>(sampledF, op_wF, out);
}

// Round 2
// 205.851 us; speedup vs baseline: 1.1186x; 1.1186x over previous
//
#include <hip/hip_runtime.h>

// DCNv4 on gfx950 — bf16 MFMA pipeline, fragment-swizzled operands.
// R9: om GEMM fused INTO the sampler (oms_kernel). Block = (img, g, quarter).
//  - om_w g-slice (27->32 padded cols) kept in 64 VGPRs as B-frags, reused
//    across 1024 pixels; A-frags (xdwF) stream from L2 (img<->XCD affinity).
//  - swapped mfma(w,x) -> D[j][pix]: lane holds 4 consecutive j for one pixel
//    -> f32 per-wave s_om[64px][32j] (128B rows, XOR slot swizzle, b128 I/O).
//  - value plane in zero-padded 66x66 LDS (R8 sampler structure, unchanged).
//  - omP global round-trip (94 MB HBM writes in R8) eliminated.
// KW: vp/op frag-swizzle + per-g padded om_wG
// KF: dwconv3x3 + value GEMM (block = image row) -> xdwF, value_g
// OMS: om GEMM + bilinear sampling -> sampledF (frag layout)
// K4: out = sampledF @ op_wF (M=64, fp32 NHWC out)

typedef __bf16 bf16_t;
typedef bf16_t bf16x8 __attribute__((ext_vector_type(8)));
typedef bf16_t bf16x4 __attribute__((ext_vector_type(4)));
typedef float f32x4 __attribute__((ext_vector_type(4)));

namespace {
constexpr int NN = 8, HH = 64, WW = 64, CC = 256;
constexpr int G = 32, GC = 8;
constexpr int NPIX = NN * HH * WW;            // 32768
}

// fragment-swizzled flat index for a [rows][256] bf16 matrix
__device__ __forceinline__ size_t fragIdx(int row, int c) {
  return ((size_t)(row >> 4) * 4096) + ((c >> 5) * 512) + (((c >> 3) & 3) * 128) +
         ((row & 15) * 8) + (c & 7);
}

// ---------------- KW: weights -> bf16 fragment layouts ----------------------
// b<16: vp_w  b<32: op_w  (64x64 LDS transpose, as before)
// b>=32: om_wG[g] = per-g fragment matrix [32 rows(j, 27 real)][256 cols(c)]
__global__ __launch_bounds__(256) void convert_weights_kernel(
    const float* __restrict__ om_w, const float* __restrict__ vp_w,
    const float* __restrict__ op_w, bf16_t* __restrict__ om_wG,
    bf16_t* __restrict__ vp_wF, bf16_t* __restrict__ op_wF) {
  __shared__ float s_t[64][65];
  __shared__ float s_w[256][27];
  const int b = blockIdx.x, t = threadIdx.x;
  if (b < 32) {
    const float* src;
    bf16_t* dst;
    int kt, nt;
    if (b < 16) { src = vp_w; dst = vp_wF; kt = b >> 2; nt = b & 3; }
    else        { src = op_w; dst = op_wF; kt = (b - 16) >> 2; nt = (b - 16) & 3; }
    const int nl = t & 63, kh = t >> 6;
    const int n = nt * 64 + nl;
#pragma unroll
    for (int i = 0; i < 16; ++i) {
      const int kl = kh * 16 + i;
      s_t[kl][nl] = src[(size_t)(kt * 64 + kl) * CC + n];
    }
    __syncthreads();
    const int lane = t & 63, kq = lane >> 4, n15 = lane & 15, n16 = t >> 6;
#pragma unroll
    for (int it = 0; it < 2; ++it) {
      bf16x8 v;
#pragma unroll
      for (int j = 0; j < 8; ++j)
        v[j] = (bf16_t)s_t[it * 32 + kq * 8 + j][n16 * 16 + n15];
      const size_t off = (size_t)(nt * 4 + n16) * 4096 + (size_t)(kt * 2 + it) * 512 +
                         kq * 128 + n15 * 8;
      *(bf16x8*)(dst + off) = v;
    }
  } else {
    const int g = b - 32;
    // transpose load: s_w[c][j] = om_w[c][g*27+j]
#pragma unroll
    for (int j = 0; j < 27; ++j) s_w[t][j] = om_w[(size_t)t * 864 + g * 27 + j];
    __syncthreads();
#pragma unroll
    for (int i = 0; i < 4; ++i) {
      const int chunk = i * 256 + t;  // 1024 chunks of 8 bf16
      const int tile = chunk >> 9, ks = (chunk >> 6) & 7, kq = (chunk >> 4) & 3,
                n15 = chunk & 15;
      const int j = tile * 16 + n15;
      bf16x8 v;
#pragma unroll
      for (int cl = 0; cl < 8; ++cl) {
        const int c = ks * 32 + kq * 8 + cl;
        v[cl] = (j < 27) ? (bf16_t)s_w[c][j] : (bf16_t)0.0f;
      }
      *(bf16x8*)(om_wG + ((size_t)g << 13) + (size_t)chunk * 8) = v;
    }
  }
}

// ---------------- KF: fused dwconv3x3 + value GEMM; block = one image row ----
__global__ __launch_bounds__(512, 4) void dwconv_value_kernel(
    const float* __restrict__ x, const float* __restrict__ dw_w,
    const float* __restrict__ dw_b, const bf16_t* __restrict__ vp_wF,
    const float* __restrict__ vp_b, bf16_t* __restrict__ xdwF,
    bf16_t* __restrict__ value_g) {
  __shared__ bf16_t s_xf[64 * 256];  // x bf16 fragments for this row's 4 m-tiles

  const int t = threadIdx.x;
  const int row = blockIdx.x;        // img*64 + y
  const int y = row & 63;
  const int img = row >> 6;

  // ---- Phase A: dwconv
  {
    const int cq = (t & 63) * 4;   // channel base
    const int seg = t >> 6;        // 8-px segment
    const bool up = (y > 0), dn = (y < HH - 1);
    const float* xrow = x + (size_t)row * WW * CC + cq;

    const float4 bias = *(const float4*)&dw_b[cq];
    float4 dw[9];
#pragma unroll
    for (int i = 0; i < 9; ++i) dw[i] = *(const float4*)&dw_w[(size_t)i * CC + cq];

    const float4 zero = make_float4(0.f, 0.f, 0.f, 0.f);
    auto loadcol = [&](int xx, float4 c[3]) {
      if (xx < 0 || xx >= WW) { c[0] = c[1] = c[2] = zero; return; }
      c[0] = up ? *(const float4*)(xrow + ((size_t)xx - WW) * CC) : zero;
      c[1] = *(const float4*)(xrow + (size_t)xx * CC);
      c[2] = dn ? *(const float4*)(xrow + ((size_t)xx + WW) * CC) : zero;
    };

    const int x0 = seg * 8;
    float4 cm[3], cc[3], cp[3];
    loadcol(x0 - 1, cm);
    loadcol(x0, cc);

    for (int xx = x0; xx < x0 + 8; ++xx) {
      loadcol(xx + 1, cp);
      float4 a = bias;
#pragma unroll
      for (int r = 0; r < 3; ++r) {
        const float4 w0 = dw[r * 3 + 0], w1 = dw[r * 3 + 1], w2 = dw[r * 3 + 2];
        a.x = fmaf(cm[r].x, w0.x, fmaf(cc[r].x, w1.x, fmaf(cp[r].x, w2.x, a.x)));
        a.y = fmaf(cm[r].y, w0.y, fmaf(cc[r].y, w1.y, fmaf(cp[r].y, w2.y, a.y)));
        a.z = fmaf(cm[r].z, w0.z, fmaf(cc[r].z, w1.z, fmaf(cp[r].z, w2.z, a.z)));
        a.w = fmaf(cm[r].w, w0.w, fmaf(cc[r].w, w1.w, fmaf(cp[r].w, w2.w, a.w)));
      }
      const int pix = row * WW + xx;
      bf16x4 av, cv;
      av[0] = (bf16_t)a.x; av[1] = (bf16_t)a.y; av[2] = (bf16_t)a.z; av[3] = (bf16_t)a.w;
      cv[0] = (bf16_t)cc[1].x; cv[1] = (bf16_t)cc[1].y;
      cv[2] = (bf16_t)cc[1].z; cv[3] = (bf16_t)cc[1].w;
      *(bf16x4*)&xdwF[fragIdx(pix, cq)] = av;
      const int lf = (xx >> 4) * 4096 + ((cq >> 5) * 512) + (((cq >> 3) & 3) * 128) +
                     ((xx & 15) * 8) + (cq & 7);
      *(bf16x4*)&s_xf[lf] = cv;
#pragma unroll
      for (int r = 0; r < 3; ++r) { cm[r] = cc[r]; cc[r] = cp[r]; }
    }
  }
  __syncthreads();

  // ---- Phase B: value GEMM (M=64 from LDS, N=256)
  {
    const int lane = t & 63;
    const int wave = t >> 6;
    const int mq = wave >> 1;      // m-tile 0..3
    const int nh = wave & 1;       // n-half
    const int m = lane & 15;
    const int kq = lane >> 4;

    const bf16_t* Ap = s_xf + mq * 4096 + lane * 8;
    const bf16_t* Bp = vp_wF + (size_t)(nh * 8) * 4096 + lane * 8;

    f32x4 acc[8] = {};
#pragma unroll
    for (int ks = 0; ks < 8; ++ks) {
      const bf16x8 a = *(const bf16x8*)(Ap + ks * 512);
#pragma unroll
      for (int i = 0; i < 8; ++i) {
        const bf16x8 b = *(const bf16x8*)(Bp + (size_t)i * 4096 + ks * 512);
        acc[i] = __builtin_amdgcn_mfma_f32_16x16x32_bf16(a, b, acc[i], 0, 0, 0);
      }
    }

#pragma unroll
    for (int i = 0; i < 8; ++i) {
      const int n = (nh * 8 + i) * 16 + m;
      const float bs = vp_b[n];
      const int g = n >> 3, c = n & 7;
      bf16_t* plane = value_g + ((size_t)(img * G + g) << 15) + c;
#pragma unroll
      for (int r = 0; r < 4; ++r) {
        const int pl = mq * 16 + kq * 4 + r;           // pixel local 0..63
        const int pin = y * 64 + pl;                   // pixel within image
        plane[(size_t)pin * GC] = (bf16_t)(acc[i][r] + bs);
      }
    }
  }
}

// ---------------- OMS: fused om GEMM + sampling; block = (img, g, quarter) ---
// grid b: img = b&7 (XCD affinity), g = (b>>3)&31, quarter = b>>8
__global__ __launch_bounds__(512, 2) void oms_kernel(
    const bf16_t* __restrict__ xdwF, const bf16_t* __restrict__ om_wG,
    const float* __restrict__ om_b, const bf16_t* __restrict__ value_g,
    bf16_t* __restrict__ sampledF) {
  __shared__ bf16x8 s_v[66 * 66];       // 69,696 B zero-padded value plane
  __shared__ float s_om[8][64][32];     // 65,536 B per-wave om tile (slot-swizzled)

  const int t = threadIdx.x;
  const int lane = t & 63, wave = t >> 6;
  const int b = blockIdx.x;
  const int img = b & 7, g = (b >> 3) & 31, quarter = b >> 8;
  const int c15 = lane & 15, kq = lane >> 4;
  const int tile0 = img * 256 + quarter * 64;   // global px-tile base

  // ---- B-frags (g's padded 32 om columns) into registers; reused 8x each
  bf16x8 wf[2][8];
  {
    const bf16_t* base = om_wG + ((size_t)g << 13) + (size_t)lane * 8;
#pragma unroll
    for (int n2 = 0; n2 < 2; ++n2)
#pragma unroll
      for (int ks = 0; ks < 8; ++ks)
        wf[n2][ks] = *(const bf16x8*)(base + n2 * 4096 + ks * 512);
  }
  float bias[2][4];
#pragma unroll
  for (int n2 = 0; n2 < 2; ++n2)
#pragma unroll
    for (int r = 0; r < 4; ++r) {
      const int j = n2 * 16 + kq * 4 + r;
      bias[n2][r] = (j < 27) ? om_b[g * 27 + j] : 0.0f;
    }

  // ---- stage value plane: zero border + interior
  {
    const bf16x8 zv = {};
    for (int i = t; i < 260; i += 512) {
      int Y, X;
      if (i < 66)       { Y = 0;           X = i; }
      else if (i < 132) { Y = 65;          X = i - 66; }
      else if (i < 196) { Y = i - 132 + 1; X = 0; }
      else              { Y = i - 196 + 1; X = 65; }
      s_v[Y * 66 + X] = zv;
    }
    const bf16x8* plane = (const bf16x8*)(value_g + ((size_t)(img * G + g) << 15));
#pragma unroll
    for (int i = 0; i < 8; ++i) {
      const int c = i * 512 + t;   // 0..4095
      s_v[((c >> 6) + 1) * 66 + (c & 63) + 1] = plane[c];
    }
  }

  // ---- om GEMM for one 4-tile group -> per-wave s_om (D[j][pix] orientation)
  auto do_mfma = [&](const int grp) {
    const int tb = tile0 + wave * 8 + grp * 4;
#pragma unroll
    for (int q = 0; q < 4; ++q) {
      const bf16_t* Ap = xdwF + ((size_t)(tb + q)) * 4096 + (size_t)lane * 8;
      f32x4 a0 = {}, a1 = {};
#pragma unroll
      for (int ks = 0; ks < 8; ++ks) {
        const bf16x8 xf = *(const bf16x8*)(Ap + ks * 512);
        a0 = __builtin_amdgcn_mfma_f32_16x16x32_bf16(wf[0][ks], xf, a0, 0, 0, 0);
        a1 = __builtin_amdgcn_mfma_f32_16x16x32_bf16(wf[1][ks], xf, a1, 0, 0, 0);
      }
      // lane holds j = n2*16 + kq*4 + r for pixel p = q*16 + c15
      const int p = q * 16 + c15;
      const int key = p & 7;
      f32x4 v0, v1;
#pragma unroll
      for (int r = 0; r < 4; ++r) {
        v0[r] = a0[r] + bias[0][r];
        v1[r] = a1[r] + bias[1][r];
      }
      float* row = &s_om[wave][p][0];
      *(f32x4*)(row + ((kq ^ key) << 2)) = v0;
      *(f32x4*)(row + (((4 + kq) ^ key) << 2)) = v1;
    }
  };

  // ---- sampling: lane <-> one pixel of the wave's 64-px group
  auto do_sample = [&](const int grp) {
    const int pin = quarter * 1024 + wave * 128 + grp * 64 + lane;  // in-image px
    const float* row = &s_om[wave][lane][0];
    const int key = lane & 7;
    float arr[28];
#pragma unroll
    for (int s8 = 0; s8 < 7; ++s8) {
      const f32x4 v = *(const f32x4*)(row + ((s8 ^ key) << 2));
      arr[s8 * 4 + 0] = v[0]; arr[s8 * 4 + 1] = v[1];
      arr[s8 * 4 + 2] = v[2]; arr[s8 * 4 + 3] = v[3];
    }
    const int xw = pin & 63, y = pin >> 6;

    float acc[GC];
#pragma unroll
    for (int c = 0; c < GC; ++c) acc[c] = 0.0f;

#pragma unroll
    for (int k = 0; k < 9; ++k) {
      const float pxf = (float)(xw + (k % 3) - 1) + arr[2 * k];
      const float pyf = (float)(y + (k / 3) - 1) + arr[2 * k + 1];
      const float mk = arr[18 + k];
      const float x0f = floorf(pxf), y0f = floorf(pyf);
      const float tx = pxf - x0f, ty = pyf - y0f;
      const int ix = (int)x0f, iy = (int)y0f;

      // clamp to padded range [-1,64]; border zeros kill OOB contributions
      const int iX0 = min(max(ix, -1), 64) + 1;
      const int iX1 = min(max(ix + 1, -1), 64) + 1;
      const int iY0 = min(max(iy, -1), 64) + 1;
      const int iY1 = min(max(iy + 1, -1), 64) + 1;

      const bf16x8 v00 = s_v[iY0 * 66 + iX0];
      const bf16x8 v01 = s_v[iY0 * 66 + iX1];
      const bf16x8 v10 = s_v[iY1 * 66 + iX0];
      const bf16x8 v11 = s_v[iY1 * 66 + iX1];

      const float w00 = mk * (1.0f - ty) * (1.0f - tx);
      const float w01 = mk * (1.0f - ty) * tx;
      const float w10 = mk * ty * (1.0f - tx);
      const float w11 = mk * ty * tx;

#pragma unroll
      for (int c = 0; c < GC; ++c) {
        float s = acc[c];
        s = fmaf(w00, (float)v00[c], s);
        s = fmaf(w01, (float)v01[c], s);
        s = fmaf(w10, (float)v10[c], s);
        s = fmaf(w11, (float)v11[c], s);
        acc[c] = s;
      }
    }

    bf16x8 sv;
#pragma unroll
    for (int c = 0; c < GC; ++c) sv[c] = (bf16_t)acc[c];
    *(bf16x8*)(sampledF + fragIdx(img * 4096 + pin, g * 8)) = sv;
  };

  do_mfma(0);          // overlaps with staging loads
  __syncthreads();     // s_v ready
  do_sample(0);
  do_mfma(1);
  do_sample(1);
}

// ---------------- K4: out = sampledF @ op_wF, M=64/block, fp32 NHWC ----------
__global__ __launch_bounds__(512, 4) void out_gemm_kernel(
    const bf16_t* __restrict__ AF, const bf16_t* __restrict__ BF,
    float* __restrict__ out) {
  const int lane = threadIdx.x & 63;
  const int wave = threadIdx.x >> 6;
  const int mq = wave >> 1;
  const int nh = wave & 1;
  const int mt = blockIdx.x * 4 + mq;
  const int m = lane & 15;
  const int kq = lane >> 4;

  const bf16_t* Ap = AF + (size_t)mt * 4096 + lane * 8;
  const bf16_t* Bp = BF + (size_t)(nh * 8) * 4096 + lane * 8;

  f32x4 acc[8] = {};
#pragma unroll
  for (int ks = 0; ks < 8; ++ks) {
    const bf16x8 a = *(const bf16x8*)(Ap + ks * 512);
#pragma unroll
    for (int i = 0; i < 8; ++i) {
      const bf16x8 b = *(const bf16x8*)(Bp + (size_t)i * 4096 + ks * 512);
      acc[i] = __builtin_amdgcn_mfma_f32_16x16x32_bf16(a, b, acc[i], 0, 0, 0);
    }
  }

#pragma unroll
  for (int i = 0; i < 8; ++i) {
    const int n = (nh * 8 + i) * 16 + m;
#pragma unroll
    for (int r = 0; r < 4; ++r) {
      const int pix = mt * 16 + kq * 4 + r;
      out[(size_t)pix * CC + n] = acc[i][r];
    }
  }
}

extern "C" void kernel_launch(void* const* d_in, const int* in_sizes, int n_in,
                              void* d_out, int out_size, void* d_ws, size_t ws_size,
                              hipStream_t stream) {
  const float* x = (const float*)d_in[0];
  const float* dw_w = (const float*)d_in[1];
  const float* dw_b = (const float*)d_in[2];
  const float* om_w = (const float*)d_in[3];
  const float* om_b = (const float*)d_in[4];
  const float* vp_w = (const float*)d_in[5];
  const float* vp_b = (const float*)d_in[6];
  const float* op_w = (const float*)d_in[7];
  float* out = (float*)d_out;

  // workspace layout (bytes)
  char* ws = (char*)d_ws;
  bf16_t* value_g = (bf16_t*)ws;                      // 16,777,216
  bf16_t* xdwF = (bf16_t*)(ws + 16777216);            // 16,777,216
  bf16_t* sampledF = (bf16_t*)(ws + 33554432);        // 16,777,216
  bf16_t* om_wG = (bf16_t*)(ws + 50331648);           //    524,288
  bf16_t* vp_wF = (bf16_t*)(ws + 50855936);           //    131,072
  bf16_t* op_wF = (bf16_t*)(ws + 50987008);           //    131,072

  convert_weights_kernel<<<64, 256, 0, stream>>>(om_w, vp_w, op_w,
                                                 om_wG, vp_wF, op_wF);
  dwconv_value_kernel<<<NN * HH, 512, 0, stream>>>(x, dw_w, dw_b, vp_wF, vp_b,
                                                   xdwF, value_g);
  oms_kernel<<<1024, 512, 0, stream>>>(xdwF, om_wG, om_b, value_g, sampledF);
  out_gemm_kernel<<<NPIX / 64, 512, 0, stream>>>(sampledF, op_wF, out);
}